// Round 1
// baseline (6964.708 us; speedup 1.0000x reference)
//
#include <hip/hip_runtime.h>

typedef float f4 __attribute__((ext_vector_type(4)));

#define EPSF 1e-5f
#define Bn   32
#define CIN  256
#define COUT 512
#define Hin  28
#define Win  28
#define HOo  14
#define WOo  14
#define HWIN 784
#define HWO  196
#define NPIX 6272          // Bn*HOo*WOo

#define BMr  256           // rows per block (one per thread)
#define BNc  32            // output channels per block
#define BKC  32            // channels staged per K-step
#define LPAD 257           // padded LDS row stride (floats)

// ---------------- small prep kernels ----------------

__global__ __launch_bounds__(256)
void fold_bias_k(const float* __restrict__ g, const float* __restrict__ b,
                 const float* __restrict__ m, const float* __restrict__ v,
                 float* __restrict__ out)
{
  int oc = blockIdx.x * 256 + threadIdx.x;
  if (oc < COUT) {
    float s = g[oc] / sqrtf(v[oc] + EPSF);
    out[oc] = b[oc] - m[oc] * s;
  }
}

// out[tap][c][oc] = w[oc][c][tap] * gamma[oc]*rsqrt(var[oc]+eps)
__global__ __launch_bounds__(256)
void fold_w_k(const float* __restrict__ w, const float* __restrict__ g,
              const float* __restrict__ v, float* __restrict__ out,
              int Ci, int taps)
{
  int idx = blockIdx.x * 256 + threadIdx.x;
  int total = taps * Ci * COUT;
  if (idx >= total) return;
  int oc  = idx % COUT;
  int c   = (idx / COUT) % Ci;
  int tap = idx / (COUT * Ci);
  float s = g[oc] / sqrtf(v[oc] + EPSF);
  out[idx] = w[((size_t)oc * Ci + c) * taps + tap] * s;
}

__global__ __launch_bounds__(256)
void nchw2nhwc_k(const float* __restrict__ in, float* __restrict__ out,
                 int C, int HW)
{
  __shared__ float t[32][33];
  int n  = blockIdx.z;
  int c0 = blockIdx.y * 32, hw0 = blockIdx.x * 32;
  int tx = threadIdx.x & 31, ty = threadIdx.x >> 5;   // 32 x 8
  const float* inn  = in  + (size_t)n * C * HW;
  float*       outn = out + (size_t)n * C * HW;
  #pragma unroll
  for (int i = 0; i < 32; i += 8) {
    int c = c0 + ty + i, hw = hw0 + tx;
    t[ty + i][tx] = (hw < HW) ? inn[(size_t)c * HW + hw] : 0.f;
  }
  __syncthreads();
  #pragma unroll
  for (int i = 0; i < 32; i += 8) {
    int hw = hw0 + ty + i, c = c0 + tx;
    if (hw < HW) outn[(size_t)hw * C + c] = t[tx][ty + i];
  }
}

// ---------------- conv1 (3x3 s2 p1) + downsample (1x1 s2) fused ----------------
// X: (Bn,28,28,CIN) NHWC.  W1: (9,CIN,COUT). WD: (CIN,COUT).
// step mode (ann=0): mem1/o1/m1 IF update, idb = ds conv + bd
// ann  mode (ann=1): o1 <- relu(conv+b1)*(m1>0), idb <- ds conv + bd

__global__ __launch_bounds__(256)
void conv1_ds_k(const float* __restrict__ X,
                const float* __restrict__ W1,
                const float* __restrict__ WD,
                const float* __restrict__ B1,
                const float* __restrict__ BD,
                const float* __restrict__ VTH1,
                float* __restrict__ mem1,
                float* __restrict__ m1,
                float* __restrict__ o1,
                float* __restrict__ idb,
                int ann)
{
  __shared__ float lds[BKC * LPAD];
  const int tid     = threadIdx.x;
  const int rowBase = blockIdx.x * BMr;
  const int oc0     = blockIdx.y * BNc;

  float acc[BNc], accd[BNc];
  #pragma unroll
  for (int j = 0; j < BNc; j++) { acc[j] = 0.f; accd[j] = 0.f; }

  const int srow = tid >> 3;   // 0..31
  const int slot = tid & 7;    // channel slot (4 floats)

  int gb[8], gho[8], gwo[8]; bool grv[8];
  #pragma unroll
  for (int p = 0; p < 8; p++) {
    int r = rowBase + srow + 32 * p;
    grv[p] = (r < NPIX);
    int rr = grv[p] ? r : 0;
    int b = rr / HWO; int pp = rr - b * HWO;
    int ho = pp / WOo;
    gb[p] = b; gho[p] = ho; gwo[p] = pp - ho * WOo;
  }

  f4 vreg[8];

  auto issue = [&](int s) {
    int tap = s >> 3;               // 0..8 = conv1 taps, 9 = ds
    int c0  = (s & 7) * BKC;
    int kh = tap / 3, kw = tap - (tap / 3) * 3;
    #pragma unroll
    for (int p = 0; p < 8; p++) {
      int hi, wi;
      if (tap == 9) { hi = 2 * gho[p];           wi = 2 * gwo[p]; }
      else          { hi = 2 * gho[p] + kh - 1;  wi = 2 * gwo[p] + kw - 1; }
      bool v = grv[p] && ((unsigned)hi < (unsigned)Hin) && ((unsigned)wi < (unsigned)Win);
      f4 val = {0.f, 0.f, 0.f, 0.f};
      if (v) {
        const float* src = X + ((size_t)((gb[p] * Hin + hi) * Win + wi)) * CIN + c0 + slot * 4;
        val = *(const f4*)src;
      }
      vreg[p] = val;
    }
  };

  auto write_lds = [&]() {
    #pragma unroll
    for (int p = 0; p < 8; p++) {
      int rl = srow + 32 * p;
      #pragma unroll
      for (int j = 0; j < 4; j++)
        lds[(slot * 4 + j) * LPAD + rl] = vreg[p][j];
    }
  };

  auto gemm_step = [&](const float* __restrict__ wb, float* ac) {
    #pragma unroll 4
    for (int k = 0; k < BKC; k++) {
      float a = lds[k * LPAD + tid];
      const float* __restrict__ wr = wb + (size_t)k * COUT;   // lane-uniform -> s_load
      #pragma unroll
      for (int j = 0; j < BNc; j++) ac[j] = fmaf(a, wr[j], ac[j]);
    }
  };

  issue(0);
  for (int s = 0; s < 80; ++s) {
    __syncthreads();
    write_lds();
    __syncthreads();
    if (s < 79) issue(s + 1);
    int tap = s >> 3;
    int c0  = (s & 7) * BKC;
    if (tap == 9) gemm_step(WD + (size_t)c0 * COUT + oc0, accd);
    else          gemm_step(W1 + ((size_t)tap * CIN + c0) * COUT + oc0, acc);
  }

  const int r = rowBase + tid;
  if (r < NPIX) {
    int b = r / HWO; int pp = r - b * HWO;
    size_t base = (size_t)r * COUT + oc0;
    if (!ann) {
      #pragma unroll
      for (int j = 0; j < BNc; j++) {
        float i1 = acc[j] + B1[oc0 + j];
        float mm = mem1[base + j] + i1;
        float vt = VTH1[(size_t)(oc0 + j) * HWO + pp];
        float sp = (mm >= vt) ? 1.f : 0.f;
        mem1[base + j] = mm - sp * vt;
        m1[base + j] += sp;
        o1[base + j] = sp;
        idb[base + j] = accd[j] + BD[oc0 + j];
      }
    } else {
      #pragma unroll
      for (int j = 0; j < BNc; j++) {
        float a = acc[j] + B1[oc0 + j];
        a = a > 0.f ? a : 0.f;
        a = (m1[base + j] > 0.f) ? a : 0.f;
        o1[base + j] = a;                       // a1
        idb[base + j] = accd[j] + BD[oc0 + j];  // identity
      }
    }
  }
}

// ---------------- conv2 (3x3 s1 p1 on 14x14) ----------------
// A: (NPIX, COUT) NHWC.  mode: 0 step, 1 step+write outputs, 2 ann

__global__ __launch_bounds__(256)
void conv2_k(const float* __restrict__ A,
             const float* __restrict__ W2,
             const float* __restrict__ B2,
             const float* __restrict__ IDB,
             const float* __restrict__ VTH,
             float* __restrict__ memf,
             float* __restrict__ m3,
             float* __restrict__ out0,
             float* __restrict__ out1,
             float* __restrict__ out2,
             int mode)
{
  __shared__ float lds[BKC * LPAD];
  const int tid     = threadIdx.x;
  const int rowBase = blockIdx.x * BMr;
  const int oc0     = blockIdx.y * BNc;

  float acc[BNc];
  #pragma unroll
  for (int j = 0; j < BNc; j++) acc[j] = 0.f;

  const int srow = tid >> 3;
  const int slot = tid & 7;

  int gb[8], gho[8], gwo[8]; bool grv[8];
  #pragma unroll
  for (int p = 0; p < 8; p++) {
    int r = rowBase + srow + 32 * p;
    grv[p] = (r < NPIX);
    int rr = grv[p] ? r : 0;
    int b = rr / HWO; int pp = rr - b * HWO;
    int ho = pp / WOo;
    gb[p] = b; gho[p] = ho; gwo[p] = pp - ho * WOo;
  }

  f4 vreg[8];

  auto issue = [&](int s) {
    int tap = s >> 4;               // 9 taps x 16 chunks
    int c0  = (s & 15) * BKC;
    int kh = tap / 3, kw = tap - (tap / 3) * 3;
    #pragma unroll
    for (int p = 0; p < 8; p++) {
      int hi = gho[p] + kh - 1, wi = gwo[p] + kw - 1;
      bool v = grv[p] && ((unsigned)hi < (unsigned)HOo) && ((unsigned)wi < (unsigned)WOo);
      f4 val = {0.f, 0.f, 0.f, 0.f};
      if (v) {
        const float* src = A + ((size_t)(gb[p] * HWO + hi * WOo + wi)) * COUT + c0 + slot * 4;
        val = *(const f4*)src;
      }
      vreg[p] = val;
    }
  };

  auto write_lds = [&]() {
    #pragma unroll
    for (int p = 0; p < 8; p++) {
      int rl = srow + 32 * p;
      #pragma unroll
      for (int j = 0; j < 4; j++)
        lds[(slot * 4 + j) * LPAD + rl] = vreg[p][j];
    }
  };

  auto gemm_step = [&](const float* __restrict__ wb, float* ac) {
    #pragma unroll 4
    for (int k = 0; k < BKC; k++) {
      float a = lds[k * LPAD + tid];
      const float* __restrict__ wr = wb + (size_t)k * COUT;
      #pragma unroll
      for (int j = 0; j < BNc; j++) ac[j] = fmaf(a, wr[j], ac[j]);
    }
  };

  issue(0);
  for (int s = 0; s < 144; ++s) {
    __syncthreads();
    write_lds();
    __syncthreads();
    if (s < 143) issue(s + 1);
    int tap = s >> 4;
    int c0  = (s & 15) * BKC;
    gemm_step(W2 + ((size_t)tap * COUT + c0) * COUT + oc0, acc);
  }

  const int r = rowBase + tid;
  if (r < NPIX) {
    int b = r / HWO; int pp = r - b * HWO;
    size_t base = (size_t)r * COUT + oc0;
    if (mode != 2) {
      #pragma unroll
      for (int j = 0; j < BNc; j++) {
        float outs = acc[j] + B2[oc0 + j] + IDB[base + j];
        float mf = memf[base + j] + outs;
        float vt = VTH[(size_t)(oc0 + j) * HWO + pp];
        float sp = (mf >= vt) ? 1.f : 0.f;
        memf[base + j] = mf - sp * vt;
        m3[base + j] += sp;
        if (mode == 1) {
          size_t oidx = ((size_t)b * COUT + oc0 + j) * HWO + pp;
          out0[oidx] = sp;     // o3_last
          out1[oidx] = outs;   // Iu_last
        }
      }
    } else {
      #pragma unroll
      for (int j = 0; j < BNc; j++) {
        float v = acc[j] + B2[oc0 + j] + IDB[base + j];
        v = v > 0.f ? v : 0.f;
        v = (m3[base + j] > 0.f) ? v : 0.f;
        out2[((size_t)b * COUT + oc0 + j) * HWO + pp] = v;
      }
    }
  }
}

// ---------------- launcher ----------------

extern "C" void kernel_launch(void* const* d_in, const int* in_sizes, int n_in,
                              void* d_out, int out_size, void* d_ws, size_t ws_size,
                              hipStream_t stream)
{
  const float* inp_s = (const float*)d_in[0];
  const float* inp_c = (const float*)d_in[2];
  const float* w1    = (const float*)d_in[3];
  const float* w2    = (const float*)d_in[4];
  const float* wd    = (const float*)d_in[5];
  const float* bn1g = (const float*)d_in[6],  *bn1b = (const float*)d_in[7];
  const float* bn1m = (const float*)d_in[8],  *bn1v = (const float*)d_in[9];
  const float* bn2g = (const float*)d_in[10], *bn2b = (const float*)d_in[11];
  const float* bn2m = (const float*)d_in[12], *bn2v = (const float*)d_in[13];
  const float* dsg  = (const float*)d_in[14], *dsb  = (const float*)d_in[15];
  const float* dsm  = (const float*)d_in[16], *dsv  = (const float*)d_in[17];
  const float* vth1  = (const float*)d_in[18];
  const float* vthif = (const float*)d_in[21];

  float* ws = (float*)d_ws;
  size_t off = 0;
  float* XS  = ws + off; off += (size_t)Bn * HWIN * CIN;   // transposed input (reused per step + for inp_c)
  float* W1T = ws + off; off += (size_t)9 * CIN * COUT;
  float* W2T = ws + off; off += (size_t)9 * COUT * COUT;
  float* WDT = ws + off; off += (size_t)CIN * COUT;
  float* B1V = ws + off; off += COUT;
  float* B2V = ws + off; off += COUT;
  float* BDV = ws + off; off += COUT;
  float* MEM1 = ws + off; off += (size_t)NPIX * COUT;
  float* MEMF = ws + off; off += (size_t)NPIX * COUT;
  float* M1   = ws + off; off += (size_t)NPIX * COUT;
  float* M3   = ws + off; off += (size_t)NPIX * COUT;
  float* O1   = ws + off; off += (size_t)NPIX * COUT;  // also a1 in ANN pass
  float* IDB  = ws + off; off += (size_t)NPIX * COUT;  // also identity in ANN pass

  float* out0 = (float*)d_out;
  float* out1 = out0 + (size_t)NPIX * COUT;
  float* out2 = out1 + (size_t)NPIX * COUT;

  // BN folds
  fold_bias_k<<<2, 256, 0, stream>>>(bn1g, bn1b, bn1m, bn1v, B1V);
  fold_bias_k<<<2, 256, 0, stream>>>(bn2g, bn2b, bn2m, bn2v, B2V);
  fold_bias_k<<<2, 256, 0, stream>>>(dsg,  dsb,  dsm,  dsv,  BDV);
  fold_w_k<<<(9 * CIN * COUT + 255) / 256, 256, 0, stream>>>(w1, bn1g, bn1v, W1T, CIN, 9);
  fold_w_k<<<(9 * COUT * COUT + 255) / 256, 256, 0, stream>>>(w2, bn2g, bn2v, W2T, COUT, 9);
  fold_w_k<<<(CIN * COUT + 255) / 256, 256, 0, stream>>>(wd, dsg, dsv, WDT, CIN, 1);

  size_t stateBytes = (size_t)NPIX * COUT * sizeof(float);
  hipMemsetAsync(MEM1, 0, stateBytes, stream);
  hipMemsetAsync(MEMF, 0, stateBytes, stream);
  hipMemsetAsync(M1,   0, stateBytes, stream);
  hipMemsetAsync(M3,   0, stateBytes, stream);

  dim3 tgrid((HWIN + 31) / 32, CIN / 32, Bn);
  dim3 cgrid((NPIX + BMr - 1) / BMr, COUT / BNc);   // 25 x 16

  for (int t = 0; t < 4; ++t) {
    nchw2nhwc_k<<<tgrid, 256, 0, stream>>>(inp_s + (size_t)t * Bn * CIN * HWIN, XS, CIN, HWIN);
    conv1_ds_k<<<cgrid, 256, 0, stream>>>(XS, W1T, WDT, B1V, BDV, vth1,
                                          MEM1, M1, O1, IDB, 0);
    conv2_k<<<cgrid, 256, 0, stream>>>(O1, W2T, B2V, IDB, vthif,
                                       MEMF, M3, out0, out1, out2, (t == 3) ? 1 : 0);
  }

  // ANN branch (inp_c), reuses XS / O1 / IDB buffers
  nchw2nhwc_k<<<tgrid, 256, 0, stream>>>(inp_c, XS, CIN, HWIN);
  conv1_ds_k<<<cgrid, 256, 0, stream>>>(XS, W1T, WDT, B1V, BDV, vth1,
                                        MEM1, M1, O1, IDB, 1);
  conv2_k<<<cgrid, 256, 0, stream>>>(O1, W2T, B2V, IDB, vthif,
                                     MEMF, M3, out0, out1, out2, 2);
}

// Round 6
// 5997.273 us; speedup vs baseline: 1.1613x; 1.1613x over previous
//
#include <hip/hip_runtime.h>

typedef float f4 __attribute__((ext_vector_type(4)));

#define EPSF 1e-5f
#define CIN   256
#define COUT  512
#define HIN   28
#define WIN_  28
#define HO    14
#define WO    14
#define HWO   196
#define NPIX  6272              // 32*14*14 (one app)
#define MROWS 31360             // 5 apps * NPIX
#define NTIL  123               // ceil(31360/256)

#define BMr  256                // rows per block (one per thread)
#define BNc  32                 // output channels per block
#define BKC  32                 // channels per K-step
#define LPAD 257                // padded LDS row stride (floats)

#define NS1  72                 // conv1: 9 taps * 8 chunks
#define NS2  152                // conv2: 9*16 + ds: 8

// ---------------- prep kernels (R1 verbatim) ----------------

__global__ __launch_bounds__(256)
void fold_bias_k(const float* __restrict__ g, const float* __restrict__ b,
                 const float* __restrict__ m, const float* __restrict__ v,
                 float* __restrict__ out)
{
  int oc = blockIdx.x * 256 + threadIdx.x;
  if (oc < COUT) {
    float s = g[oc] / sqrtf(v[oc] + EPSF);
    out[oc] = b[oc] - m[oc] * s;
  }
}

// out[tap][c][oc] = w[oc][c][tap] * gamma[oc]*rsqrt(var[oc]+eps)
__global__ __launch_bounds__(256)
void fold_w_k(const float* __restrict__ w, const float* __restrict__ g,
              const float* __restrict__ v, float* __restrict__ out,
              int Ci, int taps)
{
  int idx = blockIdx.x * 256 + threadIdx.x;
  int total = taps * Ci * COUT;
  if (idx >= total) return;
  int oc  = idx % COUT;
  int c   = (idx / COUT) % Ci;
  int tap = idx / (COUT * Ci);
  float s = g[oc] / sqrtf(v[oc] + EPSF);
  out[idx] = w[((size_t)oc * Ci + c) * taps + tap] * s;
}

// ---------------- conv1 batched over 5 apps (3x3 s2 p1) ----------------
// A read directly from NCHW inputs. M = 31360 rows, N = 512.

__global__ __launch_bounds__(256)
void conv1b_k(const float* __restrict__ XS,   // inp_s (4,32,256,28,28)
              const float* __restrict__ XC,   // inp_c (32,256,28,28)
              const float* __restrict__ W1,   // [tap][c][oc]
              float* __restrict__ IO)         // [31360][512]
{
  __shared__ float lds[BKC * LPAD];
  const int tid     = threadIdx.x;
  const int rowBase = blockIdx.x * BMr;
  const int oc0     = blockIdx.y * BNc;

  float acc[BNc];
  #pragma unroll
  for (int j = 0; j < BNc; j++) acc[j] = 0.f;

  const int srow = tid >> 3;   // 0..31
  const int slot = tid & 7;    // channel quad

  const float* gbase[8]; int gho[8], gwo[8]; bool grv[8];
  #pragma unroll
  for (int p = 0; p < 8; p++) {
    int r = rowBase + srow + 32 * p;
    grv[p] = (r < MROWS);
    int rr = grv[p] ? r : 0;
    int app = rr / NPIX; int pp = rr - app * NPIX;
    int b = pp / HWO; int hw = pp - b * HWO;
    gho[p] = hw / WO; gwo[p] = hw - gho[p] * WO;
    gbase[p] = (app < 4) ? (XS + (size_t)(app * 32 + b) * (CIN * 784))
                         : (XC + (size_t)b * (CIN * 784));
  }

  f4 vreg[8];

  auto issue = [&](int s) {
    int tap = s >> 3, c0 = (s & 7) << 5;
    int kh = tap / 3, kw = tap - (tap / 3) * 3;
    #pragma unroll
    for (int p = 0; p < 8; p++) {
      int hi = 2 * gho[p] + kh - 1, wi = 2 * gwo[p] + kw - 1;
      bool v = grv[p] && ((unsigned)hi < (unsigned)HIN) && ((unsigned)wi < (unsigned)WIN_);
      const float* sp_ = gbase[p] + (size_t)(c0 + slot * 4) * 784 + hi * WIN_ + wi;
      f4 val;
      #pragma unroll
      for (int j = 0; j < 4; j++) val[j] = v ? sp_[(size_t)j * 784] : 0.f;
      vreg[p] = val;
    }
  };

  auto write_lds = [&]() {
    #pragma unroll
    for (int p = 0; p < 8; p++) {
      int rl = srow + 32 * p;
      #pragma unroll
      for (int j = 0; j < 4; j++)
        lds[(slot * 4 + j) * LPAD + rl] = vreg[p][j];
    }
  };

  auto gemm_step = [&](const float* __restrict__ wb) {
    #pragma unroll 4
    for (int k = 0; k < BKC; k++) {
      float a = lds[k * LPAD + tid];
      const float* __restrict__ wr = wb + (size_t)k * COUT;   // lane-uniform -> s_load
      #pragma unroll
      for (int j = 0; j < BNc; j++) acc[j] = fmaf(a, wr[j], acc[j]);
    }
  };

  issue(0);
  for (int s = 0; s < NS1; ++s) {
    __syncthreads();
    write_lds();
    __syncthreads();
    if (s < NS1 - 1) issue(s + 1);
    int tap = s >> 3, c0 = (s & 7) << 5;
    gemm_step(W1 + ((size_t)tap * CIN + c0) * COUT + oc0);
  }

  const int r = rowBase + tid;
  if (r < MROWS) {
    #pragma unroll
    for (int j = 0; j < BNc; j++)
      IO[(size_t)r * COUT + oc0 + j] = acc[j];
  }
}

// ---------------- layer-1 scan: 4-step IF chain + ANN gating ----------------

__global__ __launch_bounds__(256)
void scan1_k(const float* __restrict__ IO, const float* __restrict__ b1v,
             const float* __restrict__ vth1,
             unsigned char* __restrict__ SP,   // [4][NPIX][512] u8 spikes
             float* __restrict__ ACT)          // [NPIX][512] gated ANN act
{
  int idx = blockIdx.x * 256 + threadIdx.x;    // NPIX*512 threads
  int oc = idx & 511, pix = idx >> 9;
  int hw = pix % HWO;
  float b1 = b1v[oc], vt = vth1[oc * HWO + hw];
  float mem = 0.f; int m1 = 0;
  #pragma unroll
  for (int t = 0; t < 4; ++t) {
    float cur = IO[((size_t)t * NPIX + pix) * 512 + oc] + b1;
    mem += cur;
    float sp = (mem >= vt) ? 1.f : 0.f;
    mem -= sp * vt;
    m1 += (sp > 0.f) ? 1 : 0;
    SP[((size_t)t * NPIX + pix) * 512 + oc] = (unsigned char)sp;
  }
  float a = IO[((size_t)4 * NPIX + pix) * 512 + oc] + b1;
  a = a > 0.f ? a : 0.f;
  ACT[(size_t)pix * 512 + oc] = (m1 > 0) ? a : 0.f;
}

// ---------------- conv2 batched (3x3 s1 p1) + ds (1x1 s2) fused along K ----------------

__global__ __launch_bounds__(256)
void conv2b_k(const unsigned char* __restrict__ SP,  // [4][NPIX][512]
              const float* __restrict__ ACT,         // [NPIX][512]
              const float* __restrict__ XS,          // inp_s NCHW
              const float* __restrict__ XC,          // inp_c NCHW
              const float* __restrict__ W2,          // [tap][c][oc]
              const float* __restrict__ WD,          // [c][oc]
              float* __restrict__ IO)                // out: [31360][512]
{
  __shared__ float lds[BKC * LPAD];
  const int tid     = threadIdx.x;
  const int rowBase = blockIdx.x * BMr;
  const int oc0     = blockIdx.y * BNc;

  float acc[BNc];
  #pragma unroll
  for (int j = 0; j < BNc; j++) acc[j] = 0.f;

  const int srow = tid >> 3;
  const int slot = tid & 7;

  const float* gxbase[8]; int gapp[8], gb[8], gho[8], gwo[8]; bool grv[8];
  #pragma unroll
  for (int p = 0; p < 8; p++) {
    int r = rowBase + srow + 32 * p;
    grv[p] = (r < MROWS);
    int rr = grv[p] ? r : 0;
    int app = rr / NPIX; int pp = rr - app * NPIX;
    int b = pp / HWO; int hw = pp - b * HWO;
    gapp[p] = app; gb[p] = b;
    gho[p] = hw / WO; gwo[p] = hw - gho[p] * WO;
    gxbase[p] = (app < 4) ? (XS + (size_t)(app * 32 + b) * (CIN * 784))
                          : (XC + (size_t)b * (CIN * 784));
  }

  f4 vreg[8];

  auto issue = [&](int s) {
    if (s < 144) {
      int tap = s >> 4, c0 = (s & 15) << 5;
      int kh = tap / 3, kw = tap - (tap / 3) * 3;
      #pragma unroll
      for (int p = 0; p < 8; p++) {
        int hi = gho[p] + kh - 1, wi = gwo[p] + kw - 1;
        bool v = grv[p] && ((unsigned)hi < (unsigned)HO) && ((unsigned)wi < (unsigned)WO);
        int pix2 = gb[p] * HWO + hi * WO + wi;
        f4 val = {0.f, 0.f, 0.f, 0.f};
        if (v) {
          if (gapp[p] < 4) {
            unsigned u = *(const unsigned*)(SP + ((size_t)gapp[p] * NPIX + pix2) * 512 + c0 + slot * 4);
            #pragma unroll
            for (int j = 0; j < 4; j++) val[j] = (float)((u >> (8 * j)) & 255u);
          } else {
            val = *(const f4*)(ACT + (size_t)pix2 * 512 + c0 + slot * 4);
          }
        }
        vreg[p] = val;
      }
    } else {
      int c0 = (s - 144) << 5;
      #pragma unroll
      for (int p = 0; p < 8; p++) {
        int hi = 2 * gho[p], wi = 2 * gwo[p];
        const float* sp_ = gxbase[p] + (size_t)(c0 + slot * 4) * 784 + hi * WIN_ + wi;
        f4 val;
        #pragma unroll
        for (int j = 0; j < 4; j++) val[j] = grv[p] ? sp_[(size_t)j * 784] : 0.f;
        vreg[p] = val;
      }
    }
  };

  auto write_lds = [&]() {
    #pragma unroll
    for (int p = 0; p < 8; p++) {
      int rl = srow + 32 * p;
      #pragma unroll
      for (int j = 0; j < 4; j++)
        lds[(slot * 4 + j) * LPAD + rl] = vreg[p][j];
    }
  };

  auto gemm_step = [&](const float* __restrict__ wb) {
    #pragma unroll 4
    for (int k = 0; k < BKC; k++) {
      float a = lds[k * LPAD + tid];
      const float* __restrict__ wr = wb + (size_t)k * COUT;
      #pragma unroll
      for (int j = 0; j < BNc; j++) acc[j] = fmaf(a, wr[j], acc[j]);
    }
  };

  issue(0);
  for (int s = 0; s < NS2; ++s) {
    __syncthreads();
    write_lds();
    __syncthreads();
    if (s < NS2 - 1) issue(s + 1);
    const float* wb;
    if (s < 144) {
      int tap = s >> 4, c0 = (s & 15) << 5;
      wb = W2 + ((size_t)tap * COUT + c0) * COUT + oc0;
    } else {
      int c0 = (s - 144) << 5;
      wb = WD + (size_t)c0 * COUT + oc0;
    }
    gemm_step(wb);
  }

  const int r = rowBase + tid;
  if (r < MROWS) {
    #pragma unroll
    for (int j = 0; j < BNc; j++)
      IO[(size_t)r * COUT + oc0 + j] = acc[j];
  }
}

// ---------------- final scan: memf chain + outputs (NCHW) ----------------

__global__ __launch_bounds__(256)
void final_k(const float* __restrict__ IO, const float* __restrict__ b2v,
             const float* __restrict__ bdv, const float* __restrict__ vthif,
             float* __restrict__ out0, float* __restrict__ out1,
             float* __restrict__ out2)
{
  int idx = blockIdx.x * 256 + threadIdx.x;    // NPIX*512 threads
  int oc = idx & 511, pix = idx >> 9;
  int hw = pix % HWO, b = pix / HWO;
  float bias = b2v[oc] + bdv[oc];
  float vt = vthif[oc * HWO + hw];
  float memf = 0.f; int m3 = 0; float o3 = 0.f, os3 = 0.f;
  #pragma unroll
  for (int t = 0; t < 4; ++t) {
    float os = IO[((size_t)t * NPIX + pix) * 512 + oc] + bias;
    memf += os;
    float sp = (memf >= vt) ? 1.f : 0.f;
    memf -= sp * vt;
    m3 += (sp > 0.f) ? 1 : 0;
    if (t == 3) { o3 = sp; os3 = os; }
  }
  size_t oidx = ((size_t)b * COUT + oc) * HWO + hw;
  out0[oidx] = o3;
  out1[oidx] = os3;
  float av = IO[((size_t)4 * NPIX + pix) * 512 + oc] + bias;
  av = av > 0.f ? av : 0.f;
  out2[oidx] = (m3 > 0) ? av : 0.f;
}

// ---------------- launcher ----------------

extern "C" void kernel_launch(void* const* d_in, const int* in_sizes, int n_in,
                              void* d_out, int out_size, void* d_ws, size_t ws_size,
                              hipStream_t stream)
{
  const float* inp_s = (const float*)d_in[0];
  const float* inp_c = (const float*)d_in[2];
  const float* w1    = (const float*)d_in[3];
  const float* w2    = (const float*)d_in[4];
  const float* wd    = (const float*)d_in[5];
  const float* bn1g = (const float*)d_in[6],  *bn1b = (const float*)d_in[7];
  const float* bn1m = (const float*)d_in[8],  *bn1v = (const float*)d_in[9];
  const float* bn2g = (const float*)d_in[10], *bn2b = (const float*)d_in[11];
  const float* bn2m = (const float*)d_in[12], *bn2v = (const float*)d_in[13];
  const float* dsg  = (const float*)d_in[14], *dsb  = (const float*)d_in[15];
  const float* dsm  = (const float*)d_in[16], *dsv  = (const float*)d_in[17];
  const float* vth1  = (const float*)d_in[18];
  const float* vthif = (const float*)d_in[21];

  float* ws = (float*)d_ws;
  size_t off = 0;
  float* W1T = ws + off; off += (size_t)9 * CIN * COUT;          // 4.7 MB
  float* W2T = ws + off; off += (size_t)9 * COUT * COUT;         // 9.4 MB
  float* WDT = ws + off; off += (size_t)CIN * COUT;              // 0.5 MB
  float* B1V = ws + off; off += COUT;
  float* B2V = ws + off; off += COUT;
  float* BDV = ws + off; off += COUT;
  float* IO  = ws + off; off += (size_t)MROWS * COUT;            // 64.2 MB
  float* ACT = ws + off; off += (size_t)NPIX * COUT;             // 12.85 MB
  unsigned char* SP = (unsigned char*)(ws + off);                // 12.85 MB (4 u8 planes)
  // total ~104.6 MB, safely under the R1-proven 117.4 MB bound

  float* out0 = (float*)d_out;
  float* out1 = out0 + (size_t)NPIX * COUT;
  float* out2 = out1 + (size_t)NPIX * COUT;

  fold_bias_k<<<2, 256, 0, stream>>>(bn1g, bn1b, bn1m, bn1v, B1V);
  fold_bias_k<<<2, 256, 0, stream>>>(bn2g, bn2b, bn2m, bn2v, B2V);
  fold_bias_k<<<2, 256, 0, stream>>>(dsg,  dsb,  dsm,  dsv,  BDV);
  fold_w_k<<<(9 * CIN * COUT + 255) / 256, 256, 0, stream>>>(w1, bn1g, bn1v, W1T, CIN, 9);
  fold_w_k<<<(9 * COUT * COUT + 255) / 256, 256, 0, stream>>>(w2, bn2g, bn2v, W2T, COUT, 9);
  fold_w_k<<<(CIN * COUT + 255) / 256, 256, 0, stream>>>(wd, dsg, dsv, WDT, CIN, 1);

  dim3 cgrid(NTIL, COUT / BNc);                 // 123 x 16
  const int scanGrid = (NPIX * COUT) / 256;     // 12544

  conv1b_k<<<cgrid, 256, 0, stream>>>(inp_s, inp_c, W1T, IO);
  scan1_k<<<scanGrid, 256, 0, stream>>>(IO, B1V, vth1, SP, ACT);
  conv2b_k<<<cgrid, 256, 0, stream>>>(SP, ACT, inp_s, inp_c, W2T, WDT, IO);
  final_k<<<scanGrid, 256, 0, stream>>>(IO, B2V, BDV, vthif, out0, out1, out2);
}

// Round 7
// 5303.855 us; speedup vs baseline: 1.3131x; 1.1307x over previous
//
#include <hip/hip_runtime.h>

typedef float f4 __attribute__((ext_vector_type(4)));

#define EPSF 1e-5f
#define CIN   256
#define COUT  512
#define HIN   28
#define WIN_  28
#define HO    14
#define WO    14
#define HWO   196
#define NPIX  6272              // 32*14*14 (one app)
#define MROWS 31360             // 5 apps * NPIX
#define NTIL  123               // ceil(31360/256)

#define BMr  256                // rows per block (one per thread)
#define BNc  64                 // output channels per block
#define BKC  32                 // channels per K-step
#define LPAD 257                // padded LDS row stride (floats)

#define NS1  72                 // conv1: 9 taps * 8 chunks
#define NS2  152                // conv2: 9*16 + ds: 8

// ---------------- prep kernels ----------------

__global__ __launch_bounds__(256)
void fold_bias_k(const float* __restrict__ g, const float* __restrict__ b,
                 const float* __restrict__ m, const float* __restrict__ v,
                 float* __restrict__ out)
{
  int oc = blockIdx.x * 256 + threadIdx.x;
  if (oc < COUT) {
    float s = g[oc] / sqrtf(v[oc] + EPSF);
    out[oc] = b[oc] - m[oc] * s;
  }
}

// out[tap][c][oc] = w[oc][c][tap] * gamma[oc]*rsqrt(var[oc]+eps)
__global__ __launch_bounds__(256)
void fold_w_k(const float* __restrict__ w, const float* __restrict__ g,
              const float* __restrict__ v, float* __restrict__ out,
              int Ci, int taps)
{
  int idx = blockIdx.x * 256 + threadIdx.x;
  int total = taps * Ci * COUT;
  if (idx >= total) return;
  int oc  = idx % COUT;
  int c   = (idx / COUT) % Ci;
  int tap = idx / (COUT * Ci);
  float s = g[oc] / sqrtf(v[oc] + EPSF);
  out[idx] = w[((size_t)oc * Ci + c) * taps + tap] * s;
}

// ---------------- conv1 batched over 5 apps (3x3 s2 p1) ----------------
// A read directly from NCHW inputs. M = 31360 rows, N = 512.
// blockIdx.x = oc-tile (8)  -> XCD-pinned weight slice
// blockIdx.y = M-tile (123)

__global__ __launch_bounds__(256)
void conv1b_k(const float* __restrict__ XS,   // inp_s (4,32,256,28,28)
              const float* __restrict__ XC,   // inp_c (32,256,28,28)
              const float* __restrict__ W1,   // [tap][c][oc]
              float* __restrict__ IO)         // [31360][512]
{
  __shared__ float lds[BKC * LPAD];
  const int tid     = threadIdx.x;
  const int oc0     = blockIdx.x * BNc;
  const int rowBase = blockIdx.y * BMr;

  float acc[BNc];
  #pragma unroll
  for (int j = 0; j < BNc; j++) acc[j] = 0.f;

  // lane remap: adjacent lanes -> consecutive pixels (coalesced NCHW gather)
  const int srow = tid & 31;   // pixel within 32-group
  const int slot = tid >> 5;   // channel quad (0..7)

  const float* gbase[8]; int gho[8], gwo[8]; bool grv[8];
  #pragma unroll
  for (int p = 0; p < 8; p++) {
    int r = rowBase + srow + 32 * p;
    grv[p] = (r < MROWS);
    int rr = grv[p] ? r : 0;
    int app = rr / NPIX; int pp = rr - app * NPIX;
    int b = pp / HWO; int hw = pp - b * HWO;
    gho[p] = hw / WO; gwo[p] = hw - gho[p] * WO;
    gbase[p] = (app < 4) ? (XS + (size_t)(app * 32 + b) * (CIN * 784))
                         : (XC + (size_t)b * (CIN * 784));
  }

  f4 vreg[8];

  auto issue = [&](int s) {
    int tap = s >> 3, c0 = (s & 7) << 5;
    int kh = tap / 3, kw = tap - (tap / 3) * 3;
    #pragma unroll
    for (int p = 0; p < 8; p++) {
      int hi = 2 * gho[p] + kh - 1, wi = 2 * gwo[p] + kw - 1;
      bool v = grv[p] && ((unsigned)hi < (unsigned)HIN) && ((unsigned)wi < (unsigned)WIN_);
      const float* sp_ = gbase[p] + (size_t)(c0 + slot * 4) * 784 + hi * WIN_ + wi;
      f4 val;
      #pragma unroll
      for (int j = 0; j < 4; j++) val[j] = v ? sp_[(size_t)j * 784] : 0.f;
      vreg[p] = val;
    }
  };

  auto write_lds = [&]() {
    #pragma unroll
    for (int p = 0; p < 8; p++) {
      int rl = srow + 32 * p;
      #pragma unroll
      for (int j = 0; j < 4; j++)
        lds[(slot * 4 + j) * LPAD + rl] = vreg[p][j];
    }
  };

  auto gemm_step = [&](const float* __restrict__ wb) {
    #pragma unroll 2
    for (int k = 0; k < BKC; k++) {
      float a = lds[k * LPAD + tid];
      const float* __restrict__ wr = wb + (size_t)k * COUT;   // lane-uniform -> s_load
      #pragma unroll
      for (int j = 0; j < BNc; j++) acc[j] = fmaf(a, wr[j], acc[j]);
    }
  };

  issue(0);
  for (int s = 0; s < NS1; ++s) {
    __syncthreads();
    write_lds();
    __syncthreads();
    if (s < NS1 - 1) issue(s + 1);
    int tap = s >> 3, c0 = (s & 7) << 5;
    gemm_step(W1 + ((size_t)tap * CIN + c0) * COUT + oc0);
  }

  const int r = rowBase + tid;
  if (r < MROWS) {
    #pragma unroll
    for (int j = 0; j < BNc; j += 4) {
      f4 v = {acc[j], acc[j + 1], acc[j + 2], acc[j + 3]};
      *(f4*)&IO[(size_t)r * COUT + oc0 + j] = v;
    }
  }
}

// ---------------- layer-1 scan: 4-step IF chain + ANN gating ----------------

__global__ __launch_bounds__(256)
void scan1_k(const float* __restrict__ IO, const float* __restrict__ b1v,
             const float* __restrict__ vth1,
             unsigned char* __restrict__ SP,   // [4][NPIX][512] u8 spikes
             float* __restrict__ ACT)          // [NPIX][512] gated ANN act
{
  int idx = blockIdx.x * 256 + threadIdx.x;    // NPIX*512 threads
  int oc = idx & 511, pix = idx >> 9;
  int hw = pix % HWO;
  float b1 = b1v[oc], vt = vth1[oc * HWO + hw];
  float mem = 0.f; int m1 = 0;
  #pragma unroll
  for (int t = 0; t < 4; ++t) {
    float cur = IO[((size_t)t * NPIX + pix) * 512 + oc] + b1;
    mem += cur;
    float sp = (mem >= vt) ? 1.f : 0.f;
    mem -= sp * vt;
    m1 += (sp > 0.f) ? 1 : 0;
    SP[((size_t)t * NPIX + pix) * 512 + oc] = (unsigned char)sp;
  }
  float a = IO[((size_t)4 * NPIX + pix) * 512 + oc] + b1;
  a = a > 0.f ? a : 0.f;
  ACT[(size_t)pix * 512 + oc] = (m1 > 0) ? a : 0.f;
}

// ---------------- conv2 batched (3x3 s1 p1) + ds (1x1 s2) fused along K ----------------

__global__ __launch_bounds__(256)
void conv2b_k(const unsigned char* __restrict__ SP,  // [4][NPIX][512]
              const float* __restrict__ ACT,         // [NPIX][512]
              const float* __restrict__ XS,          // inp_s NCHW
              const float* __restrict__ XC,          // inp_c NCHW
              const float* __restrict__ W2,          // [tap][c][oc]
              const float* __restrict__ WD,          // [c][oc]
              float* __restrict__ IO)                // out: [31360][512]
{
  __shared__ float lds[BKC * LPAD];
  const int tid     = threadIdx.x;
  const int oc0     = blockIdx.x * BNc;
  const int rowBase = blockIdx.y * BMr;

  float acc[BNc];
  #pragma unroll
  for (int j = 0; j < BNc; j++) acc[j] = 0.f;

  // channel-contiguous sources -> keep slot in low bits (coalesced)
  const int srow = tid >> 3;
  const int slot = tid & 7;

  const float* gxbase[8]; int gapp[8], gb[8], gho[8], gwo[8]; bool grv[8];
  #pragma unroll
  for (int p = 0; p < 8; p++) {
    int r = rowBase + srow + 32 * p;
    grv[p] = (r < MROWS);
    int rr = grv[p] ? r : 0;
    int app = rr / NPIX; int pp = rr - app * NPIX;
    int b = pp / HWO; int hw = pp - b * HWO;
    gapp[p] = app; gb[p] = b;
    gho[p] = hw / WO; gwo[p] = hw - gho[p] * WO;
    gxbase[p] = (app < 4) ? (XS + (size_t)(app * 32 + b) * (CIN * 784))
                          : (XC + (size_t)b * (CIN * 784));
  }

  f4 vreg[8];

  auto issue = [&](int s) {
    if (s < 144) {
      int tap = s >> 4, c0 = (s & 15) << 5;
      int kh = tap / 3, kw = tap - (tap / 3) * 3;
      #pragma unroll
      for (int p = 0; p < 8; p++) {
        int hi = gho[p] + kh - 1, wi = gwo[p] + kw - 1;
        bool v = grv[p] && ((unsigned)hi < (unsigned)HO) && ((unsigned)wi < (unsigned)WO);
        int pix2 = gb[p] * HWO + hi * WO + wi;
        f4 val = {0.f, 0.f, 0.f, 0.f};
        if (v) {
          if (gapp[p] < 4) {
            unsigned u = *(const unsigned*)(SP + ((size_t)gapp[p] * NPIX + pix2) * 512 + c0 + slot * 4);
            #pragma unroll
            for (int j = 0; j < 4; j++) val[j] = (float)((u >> (8 * j)) & 255u);
          } else {
            val = *(const f4*)(ACT + (size_t)pix2 * 512 + c0 + slot * 4);
          }
        }
        vreg[p] = val;
      }
    } else {
      int c0 = (s - 144) << 5;
      #pragma unroll
      for (int p = 0; p < 8; p++) {
        int hi = 2 * gho[p], wi = 2 * gwo[p];
        const float* sp_ = gxbase[p] + (size_t)(c0 + slot * 4) * 784 + hi * WIN_ + wi;
        f4 val;
        #pragma unroll
        for (int j = 0; j < 4; j++) val[j] = grv[p] ? sp_[(size_t)j * 784] : 0.f;
        vreg[p] = val;
      }
    }
  };

  auto write_lds = [&]() {
    #pragma unroll
    for (int p = 0; p < 8; p++) {
      int rl = srow + 32 * p;
      #pragma unroll
      for (int j = 0; j < 4; j++)
        lds[(slot * 4 + j) * LPAD + rl] = vreg[p][j];
    }
  };

  auto gemm_step = [&](const float* __restrict__ wb) {
    #pragma unroll 2
    for (int k = 0; k < BKC; k++) {
      float a = lds[k * LPAD + tid];
      const float* __restrict__ wr = wb + (size_t)k * COUT;
      #pragma unroll
      for (int j = 0; j < BNc; j++) acc[j] = fmaf(a, wr[j], acc[j]);
    }
  };

  issue(0);
  for (int s = 0; s < NS2; ++s) {
    __syncthreads();
    write_lds();
    __syncthreads();
    if (s < NS2 - 1) issue(s + 1);
    const float* wb;
    if (s < 144) {
      int tap = s >> 4, c0 = (s & 15) << 5;
      wb = W2 + ((size_t)tap * COUT + c0) * COUT + oc0;
    } else {
      int c0 = (s - 144) << 5;
      wb = WD + (size_t)c0 * COUT + oc0;
    }
    gemm_step(wb);
  }

  const int r = rowBase + tid;
  if (r < MROWS) {
    #pragma unroll
    for (int j = 0; j < BNc; j += 4) {
      f4 v = {acc[j], acc[j + 1], acc[j + 2], acc[j + 3]};
      *(f4*)&IO[(size_t)r * COUT + oc0 + j] = v;
    }
  }
}

// ---------------- final scan: memf chain + outputs (NCHW) ----------------

__global__ __launch_bounds__(256)
void final_k(const float* __restrict__ IO, const float* __restrict__ b2v,
             const float* __restrict__ bdv, const float* __restrict__ vthif,
             float* __restrict__ out0, float* __restrict__ out1,
             float* __restrict__ out2)
{
  int idx = blockIdx.x * 256 + threadIdx.x;    // NPIX*512 threads
  int oc = idx & 511, pix = idx >> 9;
  int hw = pix % HWO, b = pix / HWO;
  float bias = b2v[oc] + bdv[oc];
  float vt = vthif[oc * HWO + hw];
  float memf = 0.f; int m3 = 0; float o3 = 0.f, os3 = 0.f;
  #pragma unroll
  for (int t = 0; t < 4; ++t) {
    float os = IO[((size_t)t * NPIX + pix) * 512 + oc] + bias;
    memf += os;
    float sp = (memf >= vt) ? 1.f : 0.f;
    memf -= sp * vt;
    m3 += (sp > 0.f) ? 1 : 0;
    if (t == 3) { o3 = sp; os3 = os; }
  }
  size_t oidx = ((size_t)b * COUT + oc) * HWO + hw;
  out0[oidx] = o3;
  out1[oidx] = os3;
  float av = IO[((size_t)4 * NPIX + pix) * 512 + oc] + bias;
  av = av > 0.f ? av : 0.f;
  out2[oidx] = (m3 > 0) ? av : 0.f;
}

// ---------------- launcher ----------------

extern "C" void kernel_launch(void* const* d_in, const int* in_sizes, int n_in,
                              void* d_out, int out_size, void* d_ws, size_t ws_size,
                              hipStream_t stream)
{
  const float* inp_s = (const float*)d_in[0];
  const float* inp_c = (const float*)d_in[2];
  const float* w1    = (const float*)d_in[3];
  const float* w2    = (const float*)d_in[4];
  const float* wd    = (const float*)d_in[5];
  const float* bn1g = (const float*)d_in[6],  *bn1b = (const float*)d_in[7];
  const float* bn1m = (const float*)d_in[8],  *bn1v = (const float*)d_in[9];
  const float* bn2g = (const float*)d_in[10], *bn2b = (const float*)d_in[11];
  const float* bn2m = (const float*)d_in[12], *bn2v = (const float*)d_in[13];
  const float* dsg  = (const float*)d_in[14], *dsb  = (const float*)d_in[15];
  const float* dsm  = (const float*)d_in[16], *dsv  = (const float*)d_in[17];
  const float* vth1  = (const float*)d_in[18];
  const float* vthif = (const float*)d_in[21];

  float* ws = (float*)d_ws;
  size_t off = 0;
  float* W1T = ws + off; off += (size_t)9 * CIN * COUT;          // 4.7 MB
  float* W2T = ws + off; off += (size_t)9 * COUT * COUT;         // 9.4 MB
  float* WDT = ws + off; off += (size_t)CIN * COUT;              // 0.5 MB
  float* B1V = ws + off; off += COUT;
  float* B2V = ws + off; off += COUT;
  float* BDV = ws + off; off += COUT;
  float* IO  = ws + off; off += (size_t)MROWS * COUT;            // 64.2 MB
  float* ACT = ws + off; off += (size_t)NPIX * COUT;             // 12.85 MB
  unsigned char* SP = (unsigned char*)(ws + off);                // 12.85 MB (4 u8 planes)
  // total ~104.6 MB, safely under the R1-proven 117.4 MB bound

  float* out0 = (float*)d_out;
  float* out1 = out0 + (size_t)NPIX * COUT;
  float* out2 = out1 + (size_t)NPIX * COUT;

  fold_bias_k<<<2, 256, 0, stream>>>(bn1g, bn1b, bn1m, bn1v, B1V);
  fold_bias_k<<<2, 256, 0, stream>>>(bn2g, bn2b, bn2m, bn2v, B2V);
  fold_bias_k<<<2, 256, 0, stream>>>(dsg,  dsb,  dsm,  dsv,  BDV);
  fold_w_k<<<(9 * CIN * COUT + 255) / 256, 256, 0, stream>>>(w1, bn1g, bn1v, W1T, CIN, 9);
  fold_w_k<<<(9 * COUT * COUT + 255) / 256, 256, 0, stream>>>(w2, bn2g, bn2v, W2T, COUT, 9);
  fold_w_k<<<(CIN * COUT + 255) / 256, 256, 0, stream>>>(wd, dsg, dsv, WDT, CIN, 1);

  dim3 cgrid(COUT / BNc, NTIL);                 // 8 x 123 : x = oc-slice -> XCD-pinned
  const int scanGrid = (NPIX * COUT) / 256;     // 12544

  conv1b_k<<<cgrid, 256, 0, stream>>>(inp_s, inp_c, W1T, IO);
  scan1_k<<<scanGrid, 256, 0, stream>>>(IO, B1V, vth1, SP, ACT);
  conv2b_k<<<cgrid, 256, 0, stream>>>(SP, ACT, inp_s, inp_c, W2T, WDT, IO);
  final_k<<<scanGrid, 256, 0, stream>>>(IO, B2V, BDV, vthif, out0, out1, out2);
}

// Round 8
// 4000.312 us; speedup vs baseline: 1.7410x; 1.3259x over previous
//
#include <hip/hip_runtime.h>

typedef float f4 __attribute__((ext_vector_type(4)));

#define EPSF 1e-5f
#define CIN   256
#define COUT  512
#define HIN   28
#define WIN_  28
#define HO    14
#define WO    14
#define HWO   196
#define NPIX  6272              // 32*14*14 (one app)
#define MROWS 31360             // 5 apps * NPIX
#define NTIL  123               // ceil(31360/256)

#define BMr  256                // rows per block (one per thread)
#define BNc  64                 // output channels per block
#define BKC  16                 // channels per K-step (halved: LDS 16.4KB -> ~2x blocks/CU)
#define LPAD 257                // padded LDS row stride (floats)

#define NS1  144                // conv1: 9 taps * 16 chunks of 16
#define NS2  304                // conv2: 9*32 + ds: 16

// ---------------- prep kernels ----------------

__global__ __launch_bounds__(256)
void fold_bias_k(const float* __restrict__ g, const float* __restrict__ b,
                 const float* __restrict__ m, const float* __restrict__ v,
                 float* __restrict__ out)
{
  int oc = blockIdx.x * 256 + threadIdx.x;
  if (oc < COUT) {
    float s = g[oc] / sqrtf(v[oc] + EPSF);
    out[oc] = b[oc] - m[oc] * s;
  }
}

// out[tap][c][oc] = w[oc][c][tap] * gamma[oc]*rsqrt(var[oc]+eps)
__global__ __launch_bounds__(256)
void fold_w_k(const float* __restrict__ w, const float* __restrict__ g,
              const float* __restrict__ v, float* __restrict__ out,
              int Ci, int taps)
{
  int idx = blockIdx.x * 256 + threadIdx.x;
  int total = taps * Ci * COUT;
  if (idx >= total) return;
  int oc  = idx % COUT;
  int c   = (idx / COUT) % Ci;
  int tap = idx / (COUT * Ci);
  float s = g[oc] / sqrtf(v[oc] + EPSF);
  out[idx] = w[((size_t)oc * Ci + c) * taps + tap] * s;
}

// ---------------- conv1 batched over 5 apps (3x3 s2 p1) ----------------
// A read directly from NCHW inputs. M = 31360 rows, N = 512.
// blockIdx.x = oc-tile (8) -> XCD-pinned weight slice; blockIdx.y = M-tile.

__global__ __launch_bounds__(256)
void conv1b_k(const float* __restrict__ XS,   // inp_s (4,32,256,28,28)
              const float* __restrict__ XC,   // inp_c (32,256,28,28)
              const float* __restrict__ W1,   // [tap][c][oc]
              float* __restrict__ IO)         // [31360][512]
{
  __shared__ float lds[BKC * LPAD];
  const int tid     = threadIdx.x;
  const int oc0     = blockIdx.x * BNc;
  const int rowBase = blockIdx.y * BMr;

  float acc[BNc];
  #pragma unroll
  for (int j = 0; j < BNc; j++) acc[j] = 0.f;

  // staging map: srow = pixel group (0..63), slot = k quad (0..3)
  const int srow = tid >> 2;
  const int slot = tid & 3;

  const float* gbase[4]; int gho[4], gwo[4]; bool grv[4];
  #pragma unroll
  for (int p = 0; p < 4; p++) {
    int r = rowBase + srow + 64 * p;
    grv[p] = (r < MROWS);
    int rr = grv[p] ? r : 0;
    int app = rr / NPIX; int pp = rr - app * NPIX;
    int b = pp / HWO; int hw = pp - b * HWO;
    gho[p] = hw / WO; gwo[p] = hw - gho[p] * WO;
    gbase[p] = (app < 4) ? (XS + (size_t)(app * 32 + b) * (CIN * 784))
                         : (XC + (size_t)b * (CIN * 784));
  }

  f4 vreg[4];

  auto issue = [&](int s) {
    int tap = s >> 4, c0 = (s & 15) << 4;
    int kh = tap / 3, kw = tap - (tap / 3) * 3;
    #pragma unroll
    for (int p = 0; p < 4; p++) {
      int hi = 2 * gho[p] + kh - 1, wi = 2 * gwo[p] + kw - 1;
      bool v = grv[p] && ((unsigned)hi < (unsigned)HIN) && ((unsigned)wi < (unsigned)WIN_);
      const float* sp_ = gbase[p] + (size_t)(c0 + slot * 4) * 784 + hi * WIN_ + wi;
      f4 val;
      #pragma unroll
      for (int j = 0; j < 4; j++) val[j] = v ? sp_[(size_t)j * 784] : 0.f;
      vreg[p] = val;
    }
  };

  auto write_lds = [&]() {
    #pragma unroll
    for (int p = 0; p < 4; p++) {
      int rl = srow + 64 * p;
      #pragma unroll
      for (int j = 0; j < 4; j++)
        lds[(slot * 4 + j) * LPAD + rl] = vreg[p][j];
    }
  };

  auto gemm_step = [&](const float* __restrict__ wb) {
    #pragma unroll 2
    for (int k = 0; k < BKC; k++) {
      float a = lds[k * LPAD + tid];
      const float* __restrict__ wr = wb + (size_t)k * COUT;   // lane-uniform -> s_load
      #pragma unroll
      for (int j = 0; j < BNc; j++) acc[j] = fmaf(a, wr[j], acc[j]);
    }
  };

  issue(0);
  for (int s = 0; s < NS1; ++s) {
    __syncthreads();
    write_lds();
    __syncthreads();
    if (s < NS1 - 1) issue(s + 1);
    int tap = s >> 4, c0 = (s & 15) << 4;
    gemm_step(W1 + ((size_t)tap * CIN + c0) * COUT + oc0);
  }

  const int r = rowBase + tid;
  if (r < MROWS) {
    #pragma unroll
    for (int j = 0; j < BNc; j += 4) {
      f4 v = {acc[j], acc[j + 1], acc[j + 2], acc[j + 3]};
      *(f4*)&IO[(size_t)r * COUT + oc0 + j] = v;
    }
  }
}

// ---------------- layer-1 scan: 4-step IF chain + ANN gating ----------------

__global__ __launch_bounds__(256)
void scan1_k(const float* __restrict__ IO, const float* __restrict__ b1v,
             const float* __restrict__ vth1,
             unsigned char* __restrict__ SP,   // [4][NPIX][512] u8 spikes
             float* __restrict__ ACT)          // [NPIX][512] gated ANN act
{
  int idx = blockIdx.x * 256 + threadIdx.x;    // NPIX*512 threads
  int oc = idx & 511, pix = idx >> 9;
  int hw = pix % HWO;
  float b1 = b1v[oc], vt = vth1[oc * HWO + hw];
  float mem = 0.f; int m1 = 0;
  #pragma unroll
  for (int t = 0; t < 4; ++t) {
    float cur = IO[((size_t)t * NPIX + pix) * 512 + oc] + b1;
    mem += cur;
    float sp = (mem >= vt) ? 1.f : 0.f;
    mem -= sp * vt;
    m1 += (sp > 0.f) ? 1 : 0;
    SP[((size_t)t * NPIX + pix) * 512 + oc] = (unsigned char)sp;
  }
  float a = IO[((size_t)4 * NPIX + pix) * 512 + oc] + b1;
  a = a > 0.f ? a : 0.f;
  ACT[(size_t)pix * 512 + oc] = (m1 > 0) ? a : 0.f;
}

// ---------------- conv2 batched (3x3 s1 p1) + ds (1x1 s2) fused along K ----------------

__global__ __launch_bounds__(256)
void conv2b_k(const unsigned char* __restrict__ SP,  // [4][NPIX][512]
              const float* __restrict__ ACT,         // [NPIX][512]
              const float* __restrict__ XS,          // inp_s NCHW
              const float* __restrict__ XC,          // inp_c NCHW
              const float* __restrict__ W2,          // [tap][c][oc]
              const float* __restrict__ WD,          // [c][oc]
              float* __restrict__ IO)                // out: [31360][512]
{
  __shared__ float lds[BKC * LPAD];
  const int tid     = threadIdx.x;
  const int oc0     = blockIdx.x * BNc;
  const int rowBase = blockIdx.y * BMr;

  float acc[BNc];
  #pragma unroll
  for (int j = 0; j < BNc; j++) acc[j] = 0.f;

  const int srow = tid >> 2;
  const int slot = tid & 3;

  const float* gxbase[4]; int gapp[4], gb[4], gho[4], gwo[4]; bool grv[4];
  #pragma unroll
  for (int p = 0; p < 4; p++) {
    int r = rowBase + srow + 64 * p;
    grv[p] = (r < MROWS);
    int rr = grv[p] ? r : 0;
    int app = rr / NPIX; int pp = rr - app * NPIX;
    int b = pp / HWO; int hw = pp - b * HWO;
    gapp[p] = app; gb[p] = b;
    gho[p] = hw / WO; gwo[p] = hw - gho[p] * WO;
    gxbase[p] = (app < 4) ? (XS + (size_t)(app * 32 + b) * (CIN * 784))
                          : (XC + (size_t)b * (CIN * 784));
  }

  f4 vreg[4];

  auto issue = [&](int s) {
    if (s < 288) {
      int tap = s >> 5, c0 = (s & 31) << 4;
      int kh = tap / 3, kw = tap - (tap / 3) * 3;
      #pragma unroll
      for (int p = 0; p < 4; p++) {
        int hi = gho[p] + kh - 1, wi = gwo[p] + kw - 1;
        bool v = grv[p] && ((unsigned)hi < (unsigned)HO) && ((unsigned)wi < (unsigned)WO);
        int pix2 = gb[p] * HWO + hi * WO + wi;
        f4 val = {0.f, 0.f, 0.f, 0.f};
        if (v) {
          if (gapp[p] < 4) {
            unsigned u = *(const unsigned*)(SP + ((size_t)gapp[p] * NPIX + pix2) * 512 + c0 + slot * 4);
            #pragma unroll
            for (int j = 0; j < 4; j++) val[j] = (float)((u >> (8 * j)) & 255u);
          } else {
            val = *(const f4*)(ACT + (size_t)pix2 * 512 + c0 + slot * 4);
          }
        }
        vreg[p] = val;
      }
    } else {
      int c0 = (s - 288) << 4;
      #pragma unroll
      for (int p = 0; p < 4; p++) {
        int hi = 2 * gho[p], wi = 2 * gwo[p];
        const float* sp_ = gxbase[p] + (size_t)(c0 + slot * 4) * 784 + hi * WIN_ + wi;
        f4 val;
        #pragma unroll
        for (int j = 0; j < 4; j++) val[j] = grv[p] ? sp_[(size_t)j * 784] : 0.f;
        vreg[p] = val;
      }
    }
  };

  auto write_lds = [&]() {
    #pragma unroll
    for (int p = 0; p < 4; p++) {
      int rl = srow + 64 * p;
      #pragma unroll
      for (int j = 0; j < 4; j++)
        lds[(slot * 4 + j) * LPAD + rl] = vreg[p][j];
    }
  };

  auto gemm_step = [&](const float* __restrict__ wb) {
    #pragma unroll 2
    for (int k = 0; k < BKC; k++) {
      float a = lds[k * LPAD + tid];
      const float* __restrict__ wr = wb + (size_t)k * COUT;
      #pragma unroll
      for (int j = 0; j < BNc; j++) acc[j] = fmaf(a, wr[j], acc[j]);
    }
  };

  issue(0);
  for (int s = 0; s < NS2; ++s) {
    __syncthreads();
    write_lds();
    __syncthreads();
    if (s < NS2 - 1) issue(s + 1);
    const float* wb;
    if (s < 288) {
      int tap = s >> 5, c0 = (s & 31) << 4;
      wb = W2 + ((size_t)tap * COUT + c0) * COUT + oc0;
    } else {
      int c0 = (s - 288) << 4;
      wb = WD + (size_t)c0 * COUT + oc0;
    }
    gemm_step(wb);
  }

  const int r = rowBase + tid;
  if (r < MROWS) {
    #pragma unroll
    for (int j = 0; j < BNc; j += 4) {
      f4 v = {acc[j], acc[j + 1], acc[j + 2], acc[j + 3]};
      *(f4*)&IO[(size_t)r * COUT + oc0 + j] = v;
    }
  }
}

// ---------------- final scan: memf chain + outputs (NCHW) ----------------

__global__ __launch_bounds__(256)
void final_k(const float* __restrict__ IO, const float* __restrict__ b2v,
             const float* __restrict__ bdv, const float* __restrict__ vthif,
             float* __restrict__ out0, float* __restrict__ out1,
             float* __restrict__ out2)
{
  int idx = blockIdx.x * 256 + threadIdx.x;    // NPIX*512 threads
  int oc = idx & 511, pix = idx >> 9;
  int hw = pix % HWO, b = pix / HWO;
  float bias = b2v[oc] + bdv[oc];
  float vt = vthif[oc * HWO + hw];
  float memf = 0.f; int m3 = 0; float o3 = 0.f, os3 = 0.f;
  #pragma unroll
  for (int t = 0; t < 4; ++t) {
    float os = IO[((size_t)t * NPIX + pix) * 512 + oc] + bias;
    memf += os;
    float sp = (memf >= vt) ? 1.f : 0.f;
    memf -= sp * vt;
    m3 += (sp > 0.f) ? 1 : 0;
    if (t == 3) { o3 = sp; os3 = os; }
  }
  size_t oidx = ((size_t)b * COUT + oc) * HWO + hw;
  out0[oidx] = o3;
  out1[oidx] = os3;
  float av = IO[((size_t)4 * NPIX + pix) * 512 + oc] + bias;
  av = av > 0.f ? av : 0.f;
  out2[oidx] = (m3 > 0) ? av : 0.f;
}

// ---------------- launcher ----------------

extern "C" void kernel_launch(void* const* d_in, const int* in_sizes, int n_in,
                              void* d_out, int out_size, void* d_ws, size_t ws_size,
                              hipStream_t stream)
{
  const float* inp_s = (const float*)d_in[0];
  const float* inp_c = (const float*)d_in[2];
  const float* w1    = (const float*)d_in[3];
  const float* w2    = (const float*)d_in[4];
  const float* wd    = (const float*)d_in[5];
  const float* bn1g = (const float*)d_in[6],  *bn1b = (const float*)d_in[7];
  const float* bn1m = (const float*)d_in[8],  *bn1v = (const float*)d_in[9];
  const float* bn2g = (const float*)d_in[10], *bn2b = (const float*)d_in[11];
  const float* bn2m = (const float*)d_in[12], *bn2v = (const float*)d_in[13];
  const float* dsg  = (const float*)d_in[14], *dsb  = (const float*)d_in[15];
  const float* dsm  = (const float*)d_in[16], *dsv  = (const float*)d_in[17];
  const float* vth1  = (const float*)d_in[18];
  const float* vthif = (const float*)d_in[21];

  float* ws = (float*)d_ws;
  size_t off = 0;
  float* W1T = ws + off; off += (size_t)9 * CIN * COUT;          // 4.7 MB
  float* W2T = ws + off; off += (size_t)9 * COUT * COUT;         // 9.4 MB
  float* WDT = ws + off; off += (size_t)CIN * COUT;              // 0.5 MB
  float* B1V = ws + off; off += COUT;
  float* B2V = ws + off; off += COUT;
  float* BDV = ws + off; off += COUT;
  float* IO  = ws + off; off += (size_t)MROWS * COUT;            // 64.2 MB
  float* ACT = ws + off; off += (size_t)NPIX * COUT;             // 12.85 MB
  unsigned char* SP = (unsigned char*)(ws + off);                // 12.85 MB (4 u8 planes)
  // total ~104.6 MB, safely under the R1-proven 117.4 MB bound

  float* out0 = (float*)d_out;
  float* out1 = out0 + (size_t)NPIX * COUT;
  float* out2 = out1 + (size_t)NPIX * COUT;

  fold_bias_k<<<2, 256, 0, stream>>>(bn1g, bn1b, bn1m, bn1v, B1V);
  fold_bias_k<<<2, 256, 0, stream>>>(bn2g, bn2b, bn2m, bn2v, B2V);
  fold_bias_k<<<2, 256, 0, stream>>>(dsg,  dsb,  dsm,  dsv,  BDV);
  fold_w_k<<<(9 * CIN * COUT + 255) / 256, 256, 0, stream>>>(w1, bn1g, bn1v, W1T, CIN, 9);
  fold_w_k<<<(9 * COUT * COUT + 255) / 256, 256, 0, stream>>>(w2, bn2g, bn2v, W2T, COUT, 9);
  fold_w_k<<<(CIN * COUT + 255) / 256, 256, 0, stream>>>(wd, dsg, dsv, WDT, CIN, 1);

  dim3 cgrid(COUT / BNc, NTIL);                 // 8 x 123 : x = oc-slice -> XCD-pinned
  const int scanGrid = (NPIX * COUT) / 256;     // 12544

  conv1b_k<<<cgrid, 256, 0, stream>>>(inp_s, inp_c, W1T, IO);
  scan1_k<<<scanGrid, 256, 0, stream>>>(IO, B1V, vth1, SP, ACT);
  conv2b_k<<<cgrid, 256, 0, stream>>>(SP, ACT, inp_s, inp_c, W2T, WDT, IO);
  final_k<<<scanGrid, 256, 0, stream>>>(IO, B2V, BDV, vthif, out0, out1, out2);
}